// Round 15
// baseline (303.460 us; speedup 1.0000x reference)
//
#include <hip/hip_runtime.h>
#include <hip/hip_bf16.h>

#define BATCH 1024
#define SEQ 256
#define HIDDEN 128
#define VOCAB 60
#define TROWS 16           // rows per wave/block (MFMA n-dim fully used, no dup)
#define HSTR 136           // f16 h-row stride: 68 dw == 4 mod 32 -> b128 phases conflict-free
#define EWSTR 132          // f32 ew-row stride: 16B-aligned, token-spread banks
#define XSTR 264           // int token-row stride: 16B-aligned, 8 mod 32

typedef _Float16 f16x8 __attribute__((ext_vector_type(8)));
typedef float f32x4 __attribute__((ext_vector_type(4)));

__device__ __forceinline__ float fast_tanh(float x) {
    // tanh(x) = 1 - 2/(exp(2x)+1); exp(2x)=exp2(x*2*log2e). Branch-free, exact +-1 tails.
    float e = __builtin_amdgcn_exp2f(x * 2.8853900817779268f);
    return __builtin_fmaf(-2.0f, __builtin_amdgcn_rcpf(e + 1.0f), 1.0f);
}

// embW[v][i] = sum_j emb[v][j] * W_ih[i][j]  (fp32-exact input-projection table)
__global__ void rnn_prep_embw(const float* __restrict__ emb,
                              const float* __restrict__ W_ih,
                              float* __restrict__ embW) {
    const int v = blockIdx.x;
    const int i = threadIdx.x;
    __shared__ __align__(16) float e[HIDDEN];
    e[i] = emb[v * HIDDEN + i];
    __syncthreads();
    const float4* wrow = (const float4*)(W_ih + i * HIDDEN);
    const float4* e4 = (const float4*)e;
    float a0 = 0.f, a1 = 0.f, a2 = 0.f, a3 = 0.f;
#pragma unroll
    for (int j = 0; j < HIDDEN / 4; ++j) {
        float4 w = wrow[j];
        float4 h = e4[j];
        a0 += w.x * h.x; a1 += w.y * h.y; a2 += w.z * h.z; a3 += w.w * h.w;
    }
    embW[v * HIDDEN + i] = (a0 + a1) + (a2 + a3);
}

// 64 blocks x 64 threads: ONE wave per block, 16 real batch rows, full 128
// columns per wave (8 M-tiles, 32 MFMA/step, W_hh in 128 VGPRs). ZERO
// barriers: h is a single LDS buffer touched only by this wave (same-wave DS
// ops execute in order -> read-old-then-write-new per step is safe). Seeds
// gather fp32 from LDS ew32 straight into the MFMA C operand. Trans pipe
// (32 tanh/lane) is the intended bottleneck; MFMA + DS hide under it.
__global__ void __launch_bounds__(64, 1)
rnn_wave(const int* __restrict__ x, const int* __restrict__ lengths,
         const float* __restrict__ embW, const float* __restrict__ W_hh,
         const float* __restrict__ W_fc, const float* __restrict__ b_fc,
         float* __restrict__ out) {
    const int lane = threadIdx.x;
    const int q = lane >> 4;     // 0..3
    const int r16 = lane & 15;   // 0..15
    const int b0 = blockIdx.x * TROWS;

    __shared__ __align__(16) float ew32[VOCAB][EWSTR];   // 31680 B
    __shared__ __align__(16) _Float16 h[TROWS][HSTR];    // 4352 B
    __shared__ int xs[TROWS][XSTR];                      // 16896 B

    // Stage ew32 (fp32 seed table), tokens, zero h. Single wave: no barrier.
    for (int i = lane; i < VOCAB * (HIDDEN / 4); i += 64) {
        int v = i >> 5, c4 = i & 31;
        *(float4*)&ew32[v][c4 * 4] = *(const float4*)(embW + v * HIDDEN + c4 * 4);
    }
#pragma unroll
    for (int r = 0; r < TROWS; ++r)
        *(int4*)&xs[r][lane * 4] = *(const int4*)(x + (b0 + r) * SEQ + lane * 4);
    for (int i = lane; i < TROWS * HSTR / 2; i += 64)
        ((int*)h)[i] = 0;

    // W_hh A-frags: lane holds A[m=r16][k=kc*32+q*8+j] for M-tile mt:
    // W_hh[16*mt + r16][kc*32 + q*8 + j]. 128 VGPRs, loaded once.
    f16x8 Wf[8][4];
#pragma unroll
    for (int mt = 0; mt < 8; ++mt) {
        const float* wr = W_hh + (16 * mt + r16) * HIDDEN + q * 8;
#pragma unroll
        for (int kc = 0; kc < 4; ++kc) {
            const float* p = wr + kc * 32;
#pragma unroll
            for (int j = 0; j < 8; ++j) Wf[mt][kc][j] = (_Float16)p[j];
        }
    }

    const int mylen = lengths[b0 + r16];
    int lenmax = mylen;
#pragma unroll
    for (int m = 1; m < 16; m <<= 1)
        lenmax = max(lenmax, __shfl_xor(lenmax, m));

    int tokc = xs[r16][0];
    uint2 capP[8];
#pragma unroll
    for (int mt = 0; mt < 8; ++mt) capP[mt] = (uint2){0u, 0u};

    for (int t = 0; t < lenmax; ++t) {
        // Seeds: 8 fp32 b128 gathers straight into C accumulators.
        f32x4 C[8];
#pragma unroll
        for (int mt = 0; mt < 8; ++mt)
            C[mt] = *(const f32x4*)&ew32[tokc][16 * mt + 4 * q];

        // h B-frags: B[k][n=r16] = h[r16][k] (old value; in-order DS).
        const _Float16* hb = &h[r16][q * 8];
        f16x8 H0 = *(const f16x8*)(hb + 0);
        f16x8 H1 = *(const f16x8*)(hb + 32);
        f16x8 H2 = *(const f16x8*)(hb + 64);
        f16x8 H3 = *(const f16x8*)(hb + 96);

        // Next token (LDS, broadcast per r16).
        const int tn = (t + 1 < SEQ) ? t + 1 : SEQ - 1;
        const int tokn = xs[r16][tn];

        // 8 independent 4-deep MFMA chains.
#pragma unroll
        for (int mt = 0; mt < 8; ++mt)
            C[mt] = __builtin_amdgcn_mfma_f32_16x16x32_f16(Wf[mt][0], H0, C[mt], 0, 0, 0);
#pragma unroll
        for (int mt = 0; mt < 8; ++mt)
            C[mt] = __builtin_amdgcn_mfma_f32_16x16x32_f16(Wf[mt][1], H1, C[mt], 0, 0, 0);
#pragma unroll
        for (int mt = 0; mt < 8; ++mt)
            C[mt] = __builtin_amdgcn_mfma_f32_16x16x32_f16(Wf[mt][2], H2, C[mt], 0, 0, 0);
#pragma unroll
        for (int mt = 0; mt < 8; ++mt)
            C[mt] = __builtin_amdgcn_mfma_f32_16x16x32_f16(Wf[mt][3], H3, C[mt], 0, 0, 0);

        const bool fin = (t + 1 == mylen);
#pragma unroll
        for (int mt = 0; mt < 8; ++mt) {
            float t0 = fast_tanh(C[mt][0]);
            float t1 = fast_tanh(C[mt][1]);
            float t2 = fast_tanh(C[mt][2]);
            float t3 = fast_tanh(C[mt][3]);
            uint2 pk;
            pk.x = __builtin_bit_cast(unsigned int, __builtin_amdgcn_cvt_pkrtz(t0, t1));
            pk.y = __builtin_bit_cast(unsigned int, __builtin_amdgcn_cvt_pkrtz(t2, t3));
            if (fin) capP[mt] = pk;
            *(uint2*)&h[r16][16 * mt + 4 * q] = pk;  // h[r16][cols 16mt+4q..+3]
        }
        tokc = tokn;
    }

    // ---- FC epilogue (wave-private, MFMA): out = W_fc . h_final^T + b_fc ----
    // Final h -> the (now dead) h buffer.
#pragma unroll
    for (int mt = 0; mt < 8; ++mt)
        *(uint2*)&h[r16][16 * mt + 4 * q] = capP[mt];

    // W_fc A-frags (4 M-tiles of 16 vocab rows; clamp OOB to 59).
    f16x8 Ff[4][4];
#pragma unroll
    for (int mtp = 0; mtp < 4; ++mtp) {
        int m = 16 * mtp + r16;
        if (m > 59) m = 59;
        const float* fr = W_fc + m * HIDDEN + q * 8;
#pragma unroll
        for (int kc = 0; kc < 4; ++kc) {
            const float* p = fr + kc * 32;
#pragma unroll
            for (int j = 0; j < 8; ++j) Ff[mtp][kc][j] = (_Float16)p[j];
        }
    }

    // Final-h B-frags (same-wave in-order DS; no barrier).
    const _Float16* hb = &h[r16][q * 8];
    f16x8 G0 = *(const f16x8*)(hb + 0);
    f16x8 G1 = *(const f16x8*)(hb + 32);
    f16x8 G2 = *(const f16x8*)(hb + 64);
    f16x8 G3 = *(const f16x8*)(hb + 96);

    f32x4 O[4];
#pragma unroll
    for (int mtp = 0; mtp < 4; ++mtp) {
        int bb = 16 * mtp + 4 * q;
        if (bb > 56) bb = 56;  // clamped group's rows are never stored
        O[mtp] = *(const f32x4*)(b_fc + bb);
    }
#pragma unroll
    for (int mtp = 0; mtp < 4; ++mtp) {
        O[mtp] = __builtin_amdgcn_mfma_f32_16x16x32_f16(Ff[mtp][0], G0, O[mtp], 0, 0, 0);
        O[mtp] = __builtin_amdgcn_mfma_f32_16x16x32_f16(Ff[mtp][1], G1, O[mtp], 0, 0, 0);
        O[mtp] = __builtin_amdgcn_mfma_f32_16x16x32_f16(Ff[mtp][2], G2, O[mtp], 0, 0, 0);
        O[mtp] = __builtin_amdgcn_mfma_f32_16x16x32_f16(Ff[mtp][3], G3, O[mtp], 0, 0, 0);
    }

    // C layout: lane (q,r16) holds out[batch row r16][vocab 16mtp+4q+v].
    float* orow = out + (b0 + r16) * VOCAB;
#pragma unroll
    for (int mtp = 0; mtp < 4; ++mtp) {
#pragma unroll
        for (int v = 0; v < 4; ++v) {
            int col = 16 * mtp + 4 * q + v;
            if (col < VOCAB) orow[col] = O[mtp][v];
        }
    }
}

extern "C" void kernel_launch(void* const* d_in, const int* in_sizes, int n_in,
                              void* d_out, int out_size, void* d_ws, size_t ws_size,
                              hipStream_t stream) {
    const int* x = (const int*)d_in[0];          // [B, T] int32
    const int* lengths = (const int*)d_in[1];    // [B] int32
    const float* emb = (const float*)d_in[2];    // [V, H]
    const float* W_ih = (const float*)d_in[3];   // [H, H]
    const float* W_hh = (const float*)d_in[4];   // [H, H]
    const float* W_fc = (const float*)d_in[5];   // [V, H]
    const float* b_fc = (const float*)d_in[6];   // [V]
    float* out = (float*)d_out;                  // [B, V]

    float* embW = (float*)d_ws;                  // VOCAB*HIDDEN floats (30 KB)

    rnn_prep_embw<<<VOCAB, HIDDEN, 0, stream>>>(emb, W_ih, embW);
    rnn_wave<<<BATCH / TROWS, 64, 0, stream>>>(x, lengths, embW, W_hh, W_fc, b_fc, out);
}

// Round 16
// 197.353 us; speedup vs baseline: 1.5377x; 1.5377x over previous
//
#include <hip/hip_runtime.h>
#include <hip/hip_bf16.h>

#define BATCH 1024
#define SEQ 256
#define HIDDEN 128
#define VOCAB 60
#define ROWS 2             // real batch rows per block (MFMA n-dim aliased 8x)
#define CHUNK 16           // seed ring depth in time steps
#define ASTRIDE 160        // f16 h-row stride: 80 dw == 16 mod 32 -> r2/q windows disjoint (broadcast, conflict-free)
#define RSTR 144           // f32 ring-row stride: 144 == 16 mod 32 -> same property

typedef _Float16 f16x8 __attribute__((ext_vector_type(8)));
typedef float f32x4 __attribute__((ext_vector_type(4)));

__device__ __forceinline__ float fast_tanh(float x) {
    // tanh(x) = 1 - 2/(exp(2x)+1); exp(2x)=exp2(x*2*log2e). Branch-free, exact +-1 tails.
    float e = __builtin_amdgcn_exp2f(x * 2.8853900817779268f);
    return __builtin_fmaf(-2.0f, __builtin_amdgcn_rcpf(e + 1.0f), 1.0f);
}

// embW[v][i] = sum_j emb[v][j] * W_ih[i][j]  (fp32-exact input-projection table)
__global__ void rnn_prep_embw(const float* __restrict__ emb,
                              const float* __restrict__ W_ih,
                              float* __restrict__ embW) {
    const int v = blockIdx.x;
    const int i = threadIdx.x;
    __shared__ __align__(16) float e[HIDDEN];
    e[i] = emb[v * HIDDEN + i];
    __syncthreads();
    const float4* wrow = (const float4*)(W_ih + i * HIDDEN);
    const float4* e4 = (const float4*)e;
    float a0 = 0.f, a1 = 0.f, a2 = 0.f, a3 = 0.f;
#pragma unroll
    for (int j = 0; j < HIDDEN / 4; ++j) {
        float4 w = wrow[j];
        float4 h = e4[j];
        a0 += w.x * h.x; a1 += w.y * h.y; a2 += w.z * h.z; a3 += w.w * h.w;
    }
    embW[v * HIDDEN + i] = (a0 + a1) + (a2 + a3);
}

// 512 blocks x 256 threads (4 waves), 2 batch rows per block, 2 blocks/CU.
// Co-resident blocks are independent barrier groups: while one stalls in its
// step chain the other issues (R12 calibration: overlap is perfect and the DS
// pipe is the binding resource). Transposed recurrence z^T = W_hh * h^T;
// wave w owns z-cols [32w,32w+32) (2 M-tiles). MFMA n-dim (16) aliases the
// 2 real rows 8x -> every in-loop LDS read is a same-address broadcast
// (conflict-free by construction with ASTRIDE/RSTR == 16 mod 32); only
// r16<2 lanes write. fp32 seeds staged per-chunk into a ring with
// register-pipelined global loads (latency spans ~16 steps).
__global__ void __launch_bounds__(256)
rnn_mfma(const int* __restrict__ x, const int* __restrict__ lengths,
         const float* __restrict__ embW, const float* __restrict__ W_hh,
         const float* __restrict__ W_fc, const float* __restrict__ b_fc,
         float* __restrict__ out) {
    const int tid = threadIdx.x;
    const int wave = tid >> 6;   // 0..3
    const int lane = tid & 63;
    const int q = lane >> 4;     // 0..3
    const int r16 = lane & 15;   // MFMA n index
    const int r2 = r16 & 1;      // real batch row (aliased 8x)
    const int c0 = wave * 32;    // wave's 32 z-cols (2 M-tiles)
    const int b0 = blockIdx.x * ROWS;

    __shared__ __align__(16) float ring[CHUNK][ROWS][RSTR];   // 18432 B
    __shared__ __align__(16) _Float16 Ah[2][ROWS][ASTRIDE];   // 1280 B
    __shared__ int xs[ROWS][SEQ + 8];                         // 2112 B
    __shared__ __align__(16) float hfin[ROWS][HIDDEN];        // 1024 B
    __shared__ int lenbuf[ROWS];

    // Stage tokens + lengths; zero both h buffers.
    for (int idx = tid; idx < ROWS * SEQ; idx += 256) {
        int r = idx >> 8, t = idx & (SEQ - 1);
        xs[r][t] = x[(b0 + r) * SEQ + t];
    }
    if (tid < ROWS) lenbuf[tid] = lengths[b0 + tid];
    for (int idx = tid; idx < (int)(sizeof(Ah) / 4); idx += 256)
        ((int*)Ah)[idx] = 0;

    // Static A-frags of W_hh for this wave's 2 M-tiles (32 cols):
    // A[m=r16][k=kc*32+q*8+j] = W_hh[c0 + 16*nt + r16][kc*32+q*8+j]. 32 VGPRs.
    f16x8 Wf[2][4];
#pragma unroll
    for (int nt = 0; nt < 2; ++nt) {
        const float* wrow = W_hh + (c0 + 16 * nt + r16) * HIDDEN + q * 8;
#pragma unroll
        for (int kc = 0; kc < 4; ++kc) {
            const float* p = wrow + kc * 32;
#pragma unroll
            for (int j = 0; j < 8; ++j) Wf[nt][kc][j] = (_Float16)p[j];
        }
    }

    __syncthreads();  // xs / lenbuf / Ah visible

    const int mylen = lenbuf[r2];
    const int lenmax = max(lenbuf[0], lenbuf[1]);

    // Staging mapping: idx = tid + 256k -> (tp = idx>>6, r = (idx>>5)&1, c4 = idx&31).
    const int s_c4 = tid & 31;
    const int s_r = (tid >> 5) & 1;
    const int s_tp = tid >> 6;   // 0..3, +4 per k

    // Prefetch chunk 0 seeds into registers.
    f32x4 rg[4];
#pragma unroll
    for (int k = 0; k < 4; ++k) {
        int tok = xs[s_r][s_tp + 4 * k];
        rg[k] = *(const f32x4*)(embW + tok * HIDDEN + s_c4 * 4);
    }

    int cur = 0;
    f32x4 cap0 = {0.f, 0.f, 0.f, 0.f}, cap1 = {0.f, 0.f, 0.f, 0.f};

    for (int t0 = 0; t0 < lenmax; t0 += CHUNK) {
        // Boundary: staged regs -> ring (LDS only), then barrier.
#pragma unroll
        for (int k = 0; k < 4; ++k)
            *(f32x4*)&ring[s_tp + 4 * k][s_r][s_c4 * 4] = rg[k];
        __syncthreads();

        // Issue next chunk's global loads now; they drain at a later barrier.
        if (t0 + CHUNK < lenmax) {
            const int t0n = t0 + CHUNK;
#pragma unroll
            for (int k = 0; k < 4; ++k) {
                int tok = xs[s_r][t0n + s_tp + 4 * k];
                rg[k] = *(const f32x4*)(embW + tok * HIDDEN + s_c4 * 4);
            }
        }

        const int tend = (lenmax - t0 < CHUNK) ? lenmax - t0 : CHUNK;
        for (int tt = 0; tt < tend; ++tt) {
            // h B-frags: B[k][n=r16] = h[r2][k] (8-way broadcast, conflict-free).
            const _Float16* hb = &Ah[cur][r2][q * 8];
            f16x8 H0 = *(const f16x8*)(hb + 0);
            f16x8 H1 = *(const f16x8*)(hb + 32);
            f16x8 H2 = *(const f16x8*)(hb + 64);
            f16x8 H3 = *(const f16x8*)(hb + 96);

            // Seeds: two broadcast b128 from the ring into the C operands.
            f32x4 a0 = *(const f32x4*)&ring[tt][r2][c0 + 4 * q];
            f32x4 a1 = *(const f32x4*)&ring[tt][r2][c0 + 16 + 4 * q];
            f32x4 d0 = {0.f, 0.f, 0.f, 0.f}, d1 = {0.f, 0.f, 0.f, 0.f};
            a0 = __builtin_amdgcn_mfma_f32_16x16x32_f16(Wf[0][0], H0, a0, 0, 0, 0);
            a1 = __builtin_amdgcn_mfma_f32_16x16x32_f16(Wf[1][0], H0, a1, 0, 0, 0);
            d0 = __builtin_amdgcn_mfma_f32_16x16x32_f16(Wf[0][2], H2, d0, 0, 0, 0);
            d1 = __builtin_amdgcn_mfma_f32_16x16x32_f16(Wf[1][2], H2, d1, 0, 0, 0);
            a0 = __builtin_amdgcn_mfma_f32_16x16x32_f16(Wf[0][1], H1, a0, 0, 0, 0);
            a1 = __builtin_amdgcn_mfma_f32_16x16x32_f16(Wf[1][1], H1, a1, 0, 0, 0);
            d0 = __builtin_amdgcn_mfma_f32_16x16x32_f16(Wf[0][3], H3, d0, 0, 0, 0);
            d1 = __builtin_amdgcn_mfma_f32_16x16x32_f16(Wf[1][3], H3, d1, 0, 0, 0);
            f32x4 z0 = a0 + d0;
            f32x4 z1 = a1 + d1;

            f32x4 th0, th1;
#pragma unroll
            for (int v = 0; v < 4; ++v) {
                th0[v] = fast_tanh(z0[v]);
                th1[v] = fast_tanh(z1[v]);
            }

            uint2 p0, p1;
            p0.x = __builtin_bit_cast(unsigned int, __builtin_amdgcn_cvt_pkrtz(th0[0], th0[1]));
            p0.y = __builtin_bit_cast(unsigned int, __builtin_amdgcn_cvt_pkrtz(th0[2], th0[3]));
            p1.x = __builtin_bit_cast(unsigned int, __builtin_amdgcn_cvt_pkrtz(th1[0], th1[1]));
            p1.y = __builtin_bit_cast(unsigned int, __builtin_amdgcn_cvt_pkrtz(th1[2], th1[3]));

            const int nxt = cur ^ 1;
            if (r16 < ROWS) {  // one writer per (row, col-quad)
                *(uint2*)&Ah[nxt][r16][c0 + 4 * q] = p0;
                *(uint2*)&Ah[nxt][r16][c0 + 16 + 4 * q] = p1;
            }
            // Capture off the critical path.
            if (t0 + tt + 1 == mylen) { cap0 = th0; cap1 = th1; }
            __syncthreads();
            cur = nxt;
        }
    }

    // Final h (fp32 captures) -> hfin, then FC epilogue.
    if (r16 < ROWS) {
        *(f32x4*)&hfin[r16][c0 + 4 * q] = cap0;
        *(f32x4*)&hfin[r16][c0 + 16 + 4 * q] = cap1;
    }
    __syncthreads();

    // FC: thread (r, c) computes out[b0+r][c].  256 = 2 rows x 128 slots.
    const int r = tid >> 7;      // 0..1
    const int c = tid & 127;     // 0..127
    if (c < VOCAB) {
        const float4* hv = (const float4*)hfin[r];
        const float4* wf = (const float4*)(W_fc + c * HIDDEN);
        float a0 = 0.f, a1 = 0.f, a2 = 0.f, a3 = 0.f;
#pragma unroll
        for (int j = 0; j < HIDDEN / 4; ++j) {
            float4 h = hv[j];
            float4 w = wf[j];
            a0 += h.x * w.x; a1 += h.y * w.y; a2 += h.z * w.z; a3 += h.w * w.w;
        }
        out[(b0 + r) * VOCAB + c] = (a0 + a1) + (a2 + a3) + b_fc[c];
    }
}

extern "C" void kernel_launch(void* const* d_in, const int* in_sizes, int n_in,
                              void* d_out, int out_size, void* d_ws, size_t ws_size,
                              hipStream_t stream) {
    const int* x = (const int*)d_in[0];          // [B, T] int32
    const int* lengths = (const int*)d_in[1];    // [B] int32
    const float* emb = (const float*)d_in[2];    // [V, H]
    const float* W_ih = (const float*)d_in[3];   // [H, H]
    const float* W_hh = (const float*)d_in[4];   // [H, H]
    const float* W_fc = (const float*)d_in[5];   // [V, H]
    const float* b_fc = (const float*)d_in[6];   // [V]
    float* out = (float*)d_out;                  // [B, V]

    float* embW = (float*)d_ws;                  // VOCAB*HIDDEN floats (30 KB)

    rnn_prep_embw<<<VOCAB, HIDDEN, 0, stream>>>(emb, W_ih, embW);
    rnn_mfma<<<BATCH / ROWS, 256, 0, stream>>>(x, lengths, embW, W_hh, W_fc, b_fc, out);
}

// Round 17
// 160.976 us; speedup vs baseline: 1.8851x; 1.2260x over previous
//
#include <hip/hip_runtime.h>
#include <hip/hip_bf16.h>

#define BATCH 1024
#define SEQ 256
#define HIDDEN 128
#define VOCAB 60
#define ROWS 4             // real batch rows per block (MFMA n-dim aliased 4x)
#define CHUNK 16           // ring-buffer depth in time steps
#define ASTRIDE 144        // f16 per h row: 72 dw == 8 mod 32 -> max 2-way (free)
#define RSTR 136           // f32 per ring row: 136 == 8 mod 32 -> conflict-free b128 pattern

typedef _Float16 f16x8 __attribute__((ext_vector_type(8)));
typedef _Float16 f16x4 __attribute__((ext_vector_type(4)));
typedef float f32x4 __attribute__((ext_vector_type(4)));

__device__ __forceinline__ float fast_tanh(float x) {
    // tanh(x) = 1 - 2/(exp(2x)+1); exp(2x)=exp2(x*2*log2e). Branch-free, exact +-1 tails.
    float e = __builtin_amdgcn_exp2f(x * 2.8853900817779268f);
    return __builtin_fmaf(-2.0f, __builtin_amdgcn_rcpf(e + 1.0f), 1.0f);
}

// embW[v][i] = sum_j emb[v][j] * W_ih[i][j]  (fp32-exact input-projection table)
__global__ void rnn_prep_embw(const float* __restrict__ emb,
                              const float* __restrict__ W_ih,
                              float* __restrict__ embW) {
    const int v = blockIdx.x;
    const int i = threadIdx.x;
    __shared__ __align__(16) float e[HIDDEN];
    e[i] = emb[v * HIDDEN + i];
    __syncthreads();
    const float4* wrow = (const float4*)(W_ih + i * HIDDEN);
    const float4* e4 = (const float4*)e;
    float a0 = 0.f, a1 = 0.f, a2 = 0.f, a3 = 0.f;
#pragma unroll
    for (int j = 0; j < HIDDEN / 4; ++j) {
        float4 w = wrow[j];
        float4 h = e4[j];
        a0 += w.x * h.x; a1 += w.y * h.y; a2 += w.z * h.z; a3 += w.w * h.w;
    }
    embW[v * HIDDEN + i] = (a0 + a1) + (a2 + a3);
}

// CHAMPION STRUCTURE (R14, 101.9 us kernel): 256 blocks x 512 threads
// (8 waves, 2/SIMD), 4 batch rows per block, 1 block/CU.
// Transposed recurrence z^T = W_hh * h^T; wave w owns z-cols [16w,16w+16).
// MFMA n-dim (16) aliases the 4 real rows 4x (broadcast reads, free); only
// r16<4 lanes write h. Seed staging is software-pipelined: global embW loads
// for chunk k+1 issue into registers right after chunk k's boundary barrier
// and drain ~1000 cyc later at a step barrier (L2 latency fully hidden);
// the boundary itself only writes regs->ring. All in-loop traffic is
// conflict-free LDS (24K total conflicts measured).
// Measured floor: step = DS-pipe ~500 clk + exposed serial chain ~450 clk;
// 8 structural variants (waves, rows, dup, co-residency, barrier-free)
// all regressed — see session journal R7-R16.
__global__ void __launch_bounds__(512)
rnn_mfma(const int* __restrict__ x, const int* __restrict__ lengths,
         const float* __restrict__ embW, const float* __restrict__ W_hh,
         const float* __restrict__ W_fc, const float* __restrict__ b_fc,
         float* __restrict__ out) {
    const int tid = threadIdx.x;
    const int wave = tid >> 6;   // 0..7
    const int lane = tid & 63;
    const int q = lane >> 4;     // 0..3
    const int r16 = lane & 15;   // MFMA n index
    const int r4 = r16 & 3;      // real batch row (aliased 4x)
    const int c0 = wave * 16;    // wave's 16 z-cols
    const int b0 = blockIdx.x * ROWS;

    __shared__ __align__(16) float ring[CHUNK][ROWS][RSTR];   // 34816 B
    __shared__ __align__(16) _Float16 Ah[2][ROWS][ASTRIDE];   // 2304 B
    __shared__ int xs[ROWS][SEQ + 1];                         // 4112 B
    __shared__ __align__(16) float hfin[ROWS][HIDDEN];        // 2048 B
    __shared__ int lenbuf[ROWS];

    // Stage tokens + lengths; zero both h buffers.
    for (int idx = tid; idx < ROWS * SEQ; idx += 512) {
        int r = idx >> 8, t = idx & (SEQ - 1);
        xs[r][t] = x[(b0 + r) * SEQ + t];
    }
    if (tid < ROWS) lenbuf[tid] = lengths[b0 + tid];
    for (int idx = tid; idx < (int)(sizeof(Ah) / 4); idx += 512)
        ((int*)Ah)[idx] = 0;

    // Static A-frags of W_hh for this wave's 16-col slice:
    // A[m=r16][k=kc*32+q*8+j] = W_hh[c0 + r16][kc*32 + q*8 + j]. 16 VGPRs.
    f16x8 Wf[4];
    {
        const float* wrow = W_hh + (c0 + r16) * HIDDEN + q * 8;
#pragma unroll
        for (int kc = 0; kc < 4; ++kc) {
            const float* p = wrow + kc * 32;
#pragma unroll
            for (int j = 0; j < 8; ++j) Wf[kc][j] = (_Float16)p[j];
        }
    }

    __syncthreads();  // xs / lenbuf / Ah visible

    const int mylen = lenbuf[r4];
    int lenmax = 0;
#pragma unroll
    for (int r = 0; r < ROWS; ++r) lenmax = max(lenmax, lenbuf[r]);

    // Staging-thread mapping: idx = tid + 512k -> (tp, r, c4).
    const int s_c4 = tid & 31;
    const int s_r = (tid >> 5) & 3;
    const int s_tp = tid >> 7;   // 0..3, +4 per k

    // Prefetch chunk 0 seeds into registers.
    f32x4 rg[4];
#pragma unroll
    for (int k = 0; k < 4; ++k) {
        int tp = s_tp + 4 * k;
        int tok = xs[s_r][tp];
        rg[k] = *(const f32x4*)(embW + tok * HIDDEN + s_c4 * 4);
    }

    int cur = 0;
    f32x4 cap = {0.f, 0.f, 0.f, 0.f};

    for (int t0 = 0; t0 < lenmax; t0 += CHUNK) {
        // Boundary: staged regs -> ring (LDS only, cheap), then barrier.
#pragma unroll
        for (int k = 0; k < 4; ++k)
            *(f32x4*)&ring[s_tp + 4 * k][s_r][s_c4 * 4] = rg[k];
        __syncthreads();

        // Issue next chunk's global loads now; they complete during the
        // first couple of steps and drain harmlessly at a step barrier.
        if (t0 + CHUNK < lenmax) {
            const int t0n = t0 + CHUNK;
#pragma unroll
            for (int k = 0; k < 4; ++k) {
                int tp = s_tp + 4 * k;
                int tok = xs[s_r][t0n + tp];
                rg[k] = *(const f32x4*)(embW + tok * HIDDEN + s_c4 * 4);
            }
        }

        const int tend = (lenmax - t0 < CHUNK) ? lenmax - t0 : CHUNK;
        for (int tt = 0; tt < tend; ++tt) {
            // h B-frags: B[k][n=r16] = h[r4][k] (4-way broadcast, conflict-free).
            const _Float16* hb = &Ah[cur][r4][q * 8];
            f16x8 H0 = *(const f16x8*)(hb + 0);
            f16x8 H1 = *(const f16x8*)(hb + 32);
            f16x8 H2 = *(const f16x8*)(hb + 64);
            f16x8 H3 = *(const f16x8*)(hb + 96);

            // Seed: one conflict-free b128 from the ring, feeds C directly.
            f32x4 a = *(const f32x4*)&ring[tt][r4][c0 + 4 * q];
            f32x4 d = {0.f, 0.f, 0.f, 0.f};
            a = __builtin_amdgcn_mfma_f32_16x16x32_f16(Wf[0], H0, a, 0, 0, 0);
            d = __builtin_amdgcn_mfma_f32_16x16x32_f16(Wf[2], H2, d, 0, 0, 0);
            a = __builtin_amdgcn_mfma_f32_16x16x32_f16(Wf[1], H1, a, 0, 0, 0);
            d = __builtin_amdgcn_mfma_f32_16x16x32_f16(Wf[3], H3, d, 0, 0, 0);
            f32x4 z = a + d;

            f32x4 th;
            th[0] = fast_tanh(z[0]);
            th[1] = fast_tanh(z[1]);
            th[2] = fast_tanh(z[2]);
            th[3] = fast_tanh(z[3]);

            uint2 pk;
            pk.x = __builtin_bit_cast(unsigned int, __builtin_amdgcn_cvt_pkrtz(th[0], th[1]));
            pk.y = __builtin_bit_cast(unsigned int, __builtin_amdgcn_cvt_pkrtz(th[2], th[3]));

            const int nxt = cur ^ 1;
            if (r16 < ROWS)  // one writer per (row, col-quad)
                *(uint2*)&Ah[nxt][r16][c0 + 4 * q] = pk;
            // Capture off the critical path (after the write).
            if (t0 + tt + 1 == mylen) cap = th;
            __syncthreads();
            cur = nxt;
        }
    }

    // Final h (fp32 captures) -> hfin, then FC epilogue.
    if (r16 < ROWS)
        *(f32x4*)&hfin[r16][c0 + 4 * q] = cap;
    __syncthreads();

    // FC: thread (r, c) computes out[b0+r][c].  512 = 4 rows x 128 slots.
    const int r = tid >> 7;      // 0..3
    const int c = tid & 127;     // 0..127
    if (c < VOCAB) {
        const float4* hv = (const float4*)hfin[r];
        const float4* wf = (const float4*)(W_fc + c * HIDDEN);
        float a0 = 0.f, a1 = 0.f, a2 = 0.f, a3 = 0.f;
#pragma unroll
        for (int j = 0; j < HIDDEN / 4; ++j) {
            float4 h = hv[j];
            float4 w = wf[j];
            a0 += h.x * w.x; a1 += h.y * w.y; a2 += h.z * w.z; a3 += h.w * w.w;
        }
        out[(b0 + r) * VOCAB + c] = (a0 + a1) + (a2 + a3) + b_fc[c];
    }
}

extern "C" void kernel_launch(void* const* d_in, const int* in_sizes, int n_in,
                              void* d_out, int out_size, void* d_ws, size_t ws_size,
                              hipStream_t stream) {
    const int* x = (const int*)d_in[0];          // [B, T] int32
    const int* lengths = (const int*)d_in[1];    // [B] int32
    const float* emb = (const float*)d_in[2];    // [V, H]
    const float* W_ih = (const float*)d_in[3];   // [H, H]
    const float* W_hh = (const float*)d_in[4];   // [H, H]
    const float* W_fc = (const float*)d_in[5];   // [V, H]
    const float* b_fc = (const float*)d_in[6];   // [V]
    float* out = (float*)d_out;                  // [B, V]

    float* embW = (float*)d_ws;                  // VOCAB*HIDDEN floats (30 KB)

    rnn_prep_embw<<<VOCAB, HIDDEN, 0, stream>>>(emb, W_ih, embW);
    rnn_mfma<<<BATCH / ROWS, 512, 0, stream>>>(x, lengths, embW, W_hh, W_fc, b_fc, out);
}